// Round 1
// baseline (811.340 us; speedup 1.0000x reference)
//
#include <hip/hip_runtime.h>

// Problem constants (from setup_inputs): B=2, t=5, C=16, G=64
#define G_     64
#define G3_    (64 * 64 * 64)          // 262144
#define CCH    16
#define BB     2
#define TT     5
#define NPOSE  (BB * (TT - 1))         // 8

// ---------------------------------------------------------------------------
// Kernel 1: compose T = pose0 * inv(pose1) for each (b, j). Poses are rigid,
// so inv([R|t]) = [R^T | -R^T t] exactly (up to fp rounding).
// Output: 12 floats per pose in ws: R row-major (9) then trans (3).
// ---------------------------------------------------------------------------
__global__ void pose_kernel(const float* __restrict__ cam, float* __restrict__ T)
{
    int n = threadIdx.x;
    if (n >= NPOSE) return;
    int b = n / (TT - 1);
    int j = n % (TT - 1);
    const float* p0 = cam + (size_t)(b * TT + 0) * 16;
    const float* p1 = cam + (size_t)(b * TT + j + 1) * 16;

    float R0[3][3], t0[3], R1[3][3], t1[3];
    #pragma unroll
    for (int r = 0; r < 3; ++r) {
        #pragma unroll
        for (int c = 0; c < 3; ++c) { R0[r][c] = p0[r * 4 + c]; R1[r][c] = p1[r * 4 + c]; }
        t0[r] = p0[r * 4 + 3];
        t1[r] = p1[r * 4 + 3];
    }
    // R = R0 * R1^T ; tr = t0 - R * t1
    float R[3][3], tr[3];
    #pragma unroll
    for (int r = 0; r < 3; ++r)
        #pragma unroll
        for (int c = 0; c < 3; ++c)
            R[r][c] = R0[r][0] * R1[c][0] + R0[r][1] * R1[c][1] + R0[r][2] * R1[c][2];
    #pragma unroll
    for (int r = 0; r < 3; ++r)
        tr[r] = t0[r] - (R[r][0] * t1[0] + R[r][1] * t1[1] + R[r][2] * t1[2]);

    float* o = T + n * 12;
    #pragma unroll
    for (int r = 0; r < 3; ++r) {
        #pragma unroll
        for (int c = 0; c < 3; ++c) o[r * 3 + c] = R[r][c];
        o[9 + r] = tr[r];
    }
}

// ---------------------------------------------------------------------------
// Kernel 2: copy frame 0 for both batches (out[:,0] = voxels[:,0]).
// float4 vectorized. 2 * 16 * 64^3 floats = 2^21 float4s.
// ---------------------------------------------------------------------------
__global__ __launch_bounds__(256) void copy0_kernel(const float* __restrict__ vox,
                                                    float* __restrict__ out)
{
    int tid = blockIdx.x * 256 + threadIdx.x;          // [0, 2^21)
    int b = tid >> 20;                                  // per-batch 2^20 float4s
    int r = tid & ((1 << 20) - 1);
    size_t base = (size_t)(b * TT) * CCH * G3_;
    const float4* s = (const float4*)(vox + base);
    float4* d = (float4*)(out + base);
    d[r] = s[r];
}

// ---------------------------------------------------------------------------
// Kernel 3: trilinear warp. One thread per (pose, z, y, x); loops 16 channels.
// ---------------------------------------------------------------------------
__global__ __launch_bounds__(256) void warp_kernel(const float* __restrict__ vox,
                                                   const float* __restrict__ T,
                                                   float* __restrict__ out)
{
    int tid = blockIdx.x * 256 + threadIdx.x;          // [0, 8 * 2^18)
    int x = tid & 63;
    int y = (tid >> 6) & 63;
    int z = (tid >> 12) & 63;
    int n = tid >> 18;                                  // pose index [0,8)
    int b = n >> 2;
    int j = n & 3;

    const float* Tn = T + n * 12;
    float R00 = Tn[0], R01 = Tn[1], R02 = Tn[2];
    float R10 = Tn[3], R11 = Tn[4], R12 = Tn[5];
    float R20 = Tn[6], R21 = Tn[7], R22 = Tn[8];
    float trx = Tn[9], try_ = Tn[10], trz = Tn[11];

    // grid point: lin[i] = (i - 31.5) / 64 ; grid_coord[z][y][x] = (lx, ly, lz)
    const float S = 1.0f / 64.0f;
    float px = (x - 31.5f) * S;
    float py = (y - 31.5f) * S;
    float pz = (z - 31.5f) * S;

    float cx = R00 * px + R01 * py + R02 * pz + trx;
    float cy = R10 * px + R11 * py + R12 * pz + try_;
    float cz = R20 * px + R21 * py + R22 * pz + trz;

    // ix = ((cam/m + 1)*64 - 1)*0.5 = cam * (32/m) + 31.5 ;  m = 0.4921875
    const float SC = 32.0f / 0.4921875f;
    float ix = cx * SC + 31.5f;
    float iy = cy * SC + 31.5f;
    float iz = cz * SC + 31.5f;

    float fx = floorf(ix), fy = floorf(iy), fz = floorf(iz);
    float tx = ix - fx, ty = iy - fy, tz = iz - fz;
    int x0 = (int)fx, y0 = (int)fy, z0 = (int)fz;
    int x1 = x0 + 1, y1 = y0 + 1, z1 = z0 + 1;

    // validity (zero padding) + clamped coords
    float wx0 = ((unsigned)x0 < 64u) ? (1.0f - tx) : 0.0f;
    float wx1 = ((unsigned)x1 < 64u) ? tx : 0.0f;
    float wy0 = ((unsigned)y0 < 64u) ? (1.0f - ty) : 0.0f;
    float wy1 = ((unsigned)y1 < 64u) ? ty : 0.0f;
    float wz0 = ((unsigned)z0 < 64u) ? (1.0f - tz) : 0.0f;
    float wz1 = ((unsigned)z1 < 64u) ? tz : 0.0f;

    int xc0 = min(max(x0, 0), 63), xc1 = min(max(x1, 0), 63);
    int yc0 = min(max(y0, 0), 63), yc1 = min(max(y1, 0), 63);
    int zc0 = min(max(z0, 0), 63), zc1 = min(max(z1, 0), 63);

    int oz0 = zc0 << 12, oz1 = zc1 << 12;
    int oy0 = yc0 << 6,  oy1 = yc1 << 6;

    int o000 = oz0 + oy0 + xc0, o001 = oz0 + oy0 + xc1;
    int o010 = oz0 + oy1 + xc0, o011 = oz0 + oy1 + xc1;
    int o100 = oz1 + oy0 + xc0, o101 = oz1 + oy0 + xc1;
    int o110 = oz1 + oy1 + xc0, o111 = oz1 + oy1 + xc1;

    float w000 = wz0 * wy0 * wx0, w001 = wz0 * wy0 * wx1;
    float w010 = wz0 * wy1 * wx0, w011 = wz0 * wy1 * wx1;
    float w100 = wz1 * wy0 * wx0, w101 = wz1 * wy0 * wx1;
    float w110 = wz1 * wy1 * wx0, w111 = wz1 * wy1 * wx1;

    size_t frame_base = (size_t)(b * TT + j + 1) * CCH * G3_;
    const float* vp = vox + frame_base;
    float* op = out + frame_base + (tid & (G3_ - 1));

    #pragma unroll 4
    for (int c = 0; c < CCH; ++c) {
        const float* v = vp + (size_t)c * G3_;
        float acc = w000 * v[o000] + w001 * v[o001]
                  + w010 * v[o010] + w011 * v[o011]
                  + w100 * v[o100] + w101 * v[o101]
                  + w110 * v[o110] + w111 * v[o111];
        op[(size_t)c * G3_] = acc;
    }
}

extern "C" void kernel_launch(void* const* d_in, const int* in_sizes, int n_in,
                              void* d_out, int out_size, void* d_ws, size_t ws_size,
                              hipStream_t stream)
{
    const float* vox = (const float*)d_in[0];
    const float* cam = (const float*)d_in[1];
    float* out = (float*)d_out;
    float* Tws = (float*)d_ws;   // 8 poses * 12 floats = 384 B

    hipLaunchKernelGGL(pose_kernel, dim3(1), dim3(64), 0, stream, cam, Tws);
    hipLaunchKernelGGL(copy0_kernel, dim3(8192), dim3(256), 0, stream, vox, out);
    hipLaunchKernelGGL(warp_kernel, dim3(8192), dim3(256), 0, stream, vox, Tws, out);
}

// Round 3
// 413.186 us; speedup vs baseline: 1.9636x; 1.9636x over previous
//
#include <hip/hip_runtime.h>

// Problem constants: B=2, t=5, C=16, G=64
#define G3_    (64 * 64 * 64)          // 262144
#define CCH    16
#define BB     2
#define TT     5
#define NPOSE  8
#define LSTRIDE 17                      // padded LDS x-stride (odd -> bank spread)

// ---------------------------------------------------------------------------
// Kernel 1: T = pose0 * inv(pose1); rigid -> inv([R|t]) = [R^T | -R^T t].
// Output per pose: 9 floats R row-major + 3 floats trans.
// ---------------------------------------------------------------------------
__global__ void pose_kernel(const float* __restrict__ cam, float* __restrict__ T)
{
    int n = threadIdx.x;
    if (n >= NPOSE) return;
    int b = n / (TT - 1);
    int j = n % (TT - 1);
    const float* p0 = cam + (size_t)(b * TT + 0) * 16;
    const float* p1 = cam + (size_t)(b * TT + j + 1) * 16;

    float R0[3][3], t0[3], R1[3][3], t1[3];
    #pragma unroll
    for (int r = 0; r < 3; ++r) {
        #pragma unroll
        for (int c = 0; c < 3; ++c) { R0[r][c] = p0[r * 4 + c]; R1[r][c] = p1[r * 4 + c]; }
        t0[r] = p0[r * 4 + 3];
        t1[r] = p1[r * 4 + 3];
    }
    float R[3][3], tr[3];
    #pragma unroll
    for (int r = 0; r < 3; ++r)
        #pragma unroll
        for (int c = 0; c < 3; ++c)
            R[r][c] = R0[r][0] * R1[c][0] + R0[r][1] * R1[c][1] + R0[r][2] * R1[c][2];
    #pragma unroll
    for (int r = 0; r < 3; ++r)
        tr[r] = t0[r] - (R[r][0] * t1[0] + R[r][1] * t1[1] + R[r][2] * t1[2]);

    float* o = T + n * 12;
    #pragma unroll
    for (int r = 0; r < 3; ++r) {
        #pragma unroll
        for (int c = 0; c < 3; ++c) o[r * 3 + c] = R[r][c];
        o[9 + r] = tr[r];
    }
}

// ---------------------------------------------------------------------------
// Kernel 2: out[:,0] = voxels[:,0], float4 copy.
// ---------------------------------------------------------------------------
__global__ __launch_bounds__(256) void copy0_kernel(const float* __restrict__ vox,
                                                    float* __restrict__ out)
{
    int tid = blockIdx.x * 256 + threadIdx.x;          // [0, 2^21)
    int b = tid >> 20;
    int r = tid & ((1 << 20) - 1);
    size_t base = (size_t)(b * TT) * CCH * G3_;
    const float4* s = (const float4*)(vox + base);
    float4* d = (float4*)(out + base);
    d[r] = s[r];
}

// ---------------------------------------------------------------------------
// Kernel 3: tiled trilinear warp with LDS staging.
// Block = 8x8x8 output tile of one pose (4096 blocks, 256 threads).
// Per channel: stage the affine-preimage bbox (<=15^3) into LDS via
// coalesced row loads, then 8-corner interpolate from LDS (2 outputs/thread).
// All 6 corner coordinates are clamped INDEPENDENTLY (matches reference
// semantics; fixes the round-2 low-boundary bug where the +1 neighbor of a
// clamped base index read the wrong cell).
// ---------------------------------------------------------------------------
__global__ __launch_bounds__(256) void warp_kernel(const float* __restrict__ vox,
                                                   const float* __restrict__ T,
                                                   float* __restrict__ out)
{
    __shared__ float lds[4096];                         // 16 KB; max used idx 3822
    const int tid = threadIdx.x;
    const int bid = blockIdx.x;
    const int n   = bid >> 9;                           // pose [0,8)
    const int t6  = bid & 511;
    const int ox  = (t6 & 7) << 3;
    const int oy  = ((t6 >> 3) & 7) << 3;
    const int oz  = (t6 >> 6) << 3;
    const int b   = n >> 2, j = n & 3;

    // zero-init LDS once: cells never staged (row/slice padding) must be
    // finite for weight-0 reads (0 * finite = 0).
    #pragma unroll
    for (int i = 0; i < 16; ++i) lds[tid + i * 256] = 0.0f;

    const float* Tn = T + n * 12;
    float R00 = Tn[0], R01 = Tn[1], R02 = Tn[2];
    float R10 = Tn[3], R11 = Tn[4], R12 = Tn[5];
    float R20 = Tn[6], R21 = Tn[7], R22 = Tn[8];
    float trx = Tn[9], try_ = Tn[10], trz = Tn[11];

    // ix = ax*gx + bx*gy + cx*gz + kx  (gx,gy,gz = output voxel index)
    const float S  = 1.0f / 64.0f;
    const float SC = 32.0f / 0.4921875f;
    const float ax = SC * R00 * S, bx = SC * R01 * S, cx = SC * R02 * S;
    const float ay = SC * R10 * S, by = SC * R11 * S, cy = SC * R12 * S;
    const float az = SC * R20 * S, bz = SC * R21 * S, cz = SC * R22 * S;
    const float kx = -31.5f * (ax + bx + cx) + SC * trx + 31.5f;
    const float ky = -31.5f * (ay + by + cy) + SC * try_ + 31.5f;
    const float kz = -31.5f * (az + bz + cz) + SC * trz + 31.5f;

    // bbox of sample coords over the tile (affine -> extrema at tile corners)
    float x0a = ax * ox, x0b = ax * (ox + 7);
    float x1a = bx * oy, x1b = bx * (oy + 7);
    float x2a = cx * oz, x2b = cx * (oz + 7);
    float min_ix = kx + fminf(x0a, x0b) + fminf(x1a, x1b) + fminf(x2a, x2b);
    float max_ix = kx + fmaxf(x0a, x0b) + fmaxf(x1a, x1b) + fmaxf(x2a, x2b);
    float y0a = ay * ox, y0b = ay * (ox + 7);
    float y1a = by * oy, y1b = by * (oy + 7);
    float y2a = cy * oz, y2b = cy * (oz + 7);
    float min_iy = ky + fminf(y0a, y0b) + fminf(y1a, y1b) + fminf(y2a, y2b);
    float max_iy = ky + fmaxf(y0a, y0b) + fmaxf(y1a, y1b) + fmaxf(y2a, y2b);
    float z0a = az * ox, z0b = az * (ox + 7);
    float z1a = bz * oy, z1b = bz * (oy + 7);
    float z2a = cz * oz, z2b = cz * (oz + 7);
    float min_iz = kz + fminf(z0a, z0b) + fminf(z1a, z1b) + fminf(z2a, z2b);
    float max_iz = kz + fmaxf(z0a, z0b) + fmaxf(z1a, z1b) + fmaxf(z2a, z2b);

    int xlo = min(max((int)floorf(min_ix), 0), 63);
    int xhi = min(max((int)floorf(max_ix) + 1, 0), 63);
    int ylo = min(max((int)floorf(min_iy), 0), 63);
    int yhi = min(max((int)floorf(max_iy) + 1, 0), 63);
    int zlo = min(max((int)floorf(min_iz), 0), 63);
    int zhi = min(max((int)floorf(max_iz) + 1, 0), 63);
    int sx = xhi - xlo + 1;     // <= 15
    int sy = yhi - ylo + 1;
    int sz = zhi - zlo + 1;
    const int lstep = sy * LSTRIDE;

    // per-thread precompute for 2 outputs: weights + independently-clamped
    // corner addresses. ia[k] = {z0y0, z0y1, z1y0, z1y1} base addresses.
    float w[2][6];
    int   ia[2][4], rxa[2][2], soff[2];
    #pragma unroll
    for (int k = 0; k < 2; ++k) {
        int o  = tid + (k << 8);
        int gx = ox + (o & 7);
        int gy = oy + ((o >> 3) & 7);
        int gz = oz + (o >> 6);
        float ix = kx + ax * gx + bx * gy + cx * gz;
        float iy = ky + ay * gx + by * gy + cy * gz;
        float iz = kz + az * gx + bz * gy + cz * gz;
        float fx = floorf(ix), fy = floorf(iy), fz = floorf(iz);
        float tx = ix - fx, ty = iy - fy, tz = iz - fz;
        int X0 = (int)fx, Y0 = (int)fy, Z0 = (int)fz;
        w[k][0] = ((unsigned)X0 < 64u) ? (1.0f - tx) : 0.0f;       // wx0
        w[k][1] = ((unsigned)(X0 + 1) < 64u) ? tx : 0.0f;          // wx1
        w[k][2] = ((unsigned)Y0 < 64u) ? (1.0f - ty) : 0.0f;       // wy0
        w[k][3] = ((unsigned)(Y0 + 1) < 64u) ? ty : 0.0f;          // wy1
        w[k][4] = ((unsigned)Z0 < 64u) ? (1.0f - tz) : 0.0f;       // wz0
        w[k][5] = ((unsigned)(Z0 + 1) < 64u) ? tz : 0.0f;          // wz1
        // independent per-corner clamp in staged-bbox space. Valid corners
        // always fall inside [0, s-1]; invalid ones have weight 0 and read
        // an arbitrary finite staged cell.
        int rx0 = min(max(X0     - xlo, 0), sx - 1);
        int rx1 = min(max(X0 + 1 - xlo, 0), sx - 1);
        int ry0 = min(max(Y0     - ylo, 0), sy - 1) * LSTRIDE;
        int ry1 = min(max(Y0 + 1 - ylo, 0), sy - 1) * LSTRIDE;
        int rz0 = min(max(Z0     - zlo, 0), sz - 1) * lstep;
        int rz1 = min(max(Z0 + 1 - zlo, 0), sz - 1) * lstep;
        ia[k][0] = rz0 + ry0;
        ia[k][1] = rz0 + ry1;
        ia[k][2] = rz1 + ry0;
        ia[k][3] = rz1 + ry1;
        rxa[k][0] = rx0;
        rxa[k][1] = rx1;
        soff[k] = (gz << 12) + (gy << 6) + gx;
    }

    const size_t fb = (size_t)((b * TT + j + 1) * CCH) * G3_;
    const float* vbase = vox + fb;
    float* obase = out + fb;

    // staging assignment: 16 lanes cover x (row), 16 rows cover y; loop z.
    const int lane16 = tid & 15;
    const int row16  = tid >> 4;
    const bool act   = (lane16 < sx) && (row16 < sy);
    const int grow   = (zlo << 12) + ((ylo + row16) << 6) + xlo + lane16;
    const int lrow   = row16 * LSTRIDE + lane16;

    for (int c = 0; c < CCH; ++c) {
        __syncthreads();                 // protect LDS from previous readers
        if (act) {
            const float* gp = vbase + (size_t)c * G3_ + grow;
            int la = lrow;
            for (int zz = 0; zz < sz; ++zz) {
                lds[la] = *gp;
                gp += 4096;
                la += lstep;
            }
        }
        __syncthreads();
        float* op = obase + (size_t)c * G3_;
        #pragma unroll
        for (int k = 0; k < 2; ++k) {
            int r0 = rxa[k][0], r1 = rxa[k][1];
            float v000 = lds[ia[k][0] + r0], v001 = lds[ia[k][0] + r1];
            float v010 = lds[ia[k][1] + r0], v011 = lds[ia[k][1] + r1];
            float v100 = lds[ia[k][2] + r0], v101 = lds[ia[k][2] + r1];
            float v110 = lds[ia[k][3] + r0], v111 = lds[ia[k][3] + r1];
            float t00 = v000 * w[k][0] + v001 * w[k][1];
            float t01 = v010 * w[k][0] + v011 * w[k][1];
            float t10 = v100 * w[k][0] + v101 * w[k][1];
            float t11 = v110 * w[k][0] + v111 * w[k][1];
            float u0  = t00 * w[k][2] + t01 * w[k][3];
            float u1  = t10 * w[k][2] + t11 * w[k][3];
            op[soff[k]] = u0 * w[k][4] + u1 * w[k][5];
        }
    }
}

extern "C" void kernel_launch(void* const* d_in, const int* in_sizes, int n_in,
                              void* d_out, int out_size, void* d_ws, size_t ws_size,
                              hipStream_t stream)
{
    const float* vox = (const float*)d_in[0];
    const float* cam = (const float*)d_in[1];
    float* out = (float*)d_out;
    float* Tws = (float*)d_ws;   // 8 poses * 12 floats

    hipLaunchKernelGGL(pose_kernel, dim3(1), dim3(64), 0, stream, cam, Tws);
    hipLaunchKernelGGL(copy0_kernel, dim3(8192), dim3(256), 0, stream, vox, out);
    hipLaunchKernelGGL(warp_kernel, dim3(4096), dim3(256), 0, stream, vox, Tws, out);
}

// Round 4
// 380.943 us; speedup vs baseline: 2.1298x; 1.0846x over previous
//
#include <hip/hip_runtime.h>

// Problem constants: B=2, t=5, C=16, G=64
#define G3_    (64 * 64 * 64)          // 262144
#define CCH    16
#define TT     5
#define NPOSE  8
#define LSTRIDE 17                      // padded LDS x-stride
#define MAXZ   15                       // max bbox extent: 7*1.016*sqrt(3)+2 < 15
#define BUF    4096                     // floats per LDS buffer (max idx 3822)

// ---------------------------------------------------------------------------
// Kernel 1: T = pose0 * inv(pose1); rigid -> inv([R|t]) = [R^T | -R^T t].
// ---------------------------------------------------------------------------
__global__ void pose_kernel(const float* __restrict__ cam, float* __restrict__ T)
{
    int n = threadIdx.x;
    if (n >= NPOSE) return;
    int b = n / (TT - 1);
    int j = n % (TT - 1);
    const float* p0 = cam + (size_t)(b * TT + 0) * 16;
    const float* p1 = cam + (size_t)(b * TT + j + 1) * 16;

    float R0[3][3], t0[3], R1[3][3], t1[3];
    #pragma unroll
    for (int r = 0; r < 3; ++r) {
        #pragma unroll
        for (int c = 0; c < 3; ++c) { R0[r][c] = p0[r * 4 + c]; R1[r][c] = p1[r * 4 + c]; }
        t0[r] = p0[r * 4 + 3];
        t1[r] = p1[r * 4 + 3];
    }
    float R[3][3], tr[3];
    #pragma unroll
    for (int r = 0; r < 3; ++r)
        #pragma unroll
        for (int c = 0; c < 3; ++c)
            R[r][c] = R0[r][0] * R1[c][0] + R0[r][1] * R1[c][1] + R0[r][2] * R1[c][2];
    #pragma unroll
    for (int r = 0; r < 3; ++r)
        tr[r] = t0[r] - (R[r][0] * t1[0] + R[r][1] * t1[1] + R[r][2] * t1[2]);

    float* o = T + n * 12;
    #pragma unroll
    for (int r = 0; r < 3; ++r) {
        #pragma unroll
        for (int c = 0; c < 3; ++c) o[r * 3 + c] = R[r][c];
        o[9 + r] = tr[r];
    }
}

// ---------------------------------------------------------------------------
// Kernel 2: out[:,0] = voxels[:,0], float4 copy.
// ---------------------------------------------------------------------------
__global__ __launch_bounds__(256) void copy0_kernel(const float* __restrict__ vox,
                                                    float* __restrict__ out)
{
    int tid = blockIdx.x * 256 + threadIdx.x;          // [0, 2^21)
    int b = tid >> 20;
    int r = tid & ((1 << 20) - 1);
    size_t base = (size_t)(b * TT) * CCH * G3_;
    const float4* s = (const float4*)(vox + base);
    float4* d = (float4*)(out + base);
    d[r] = s[r];
}

// ---------------------------------------------------------------------------
// Kernel 3: tiled trilinear warp, LDS double-buffered software pipeline.
// Block = 8x8x8 output tile of one pose (4096 blocks, 256 threads).
// Iteration c: ISSUE global loads for channel c+1 (regs, no wait) ->
// interpolate channel c from buf[c&1] -> ds_write regs to buf[(c+1)&1] ->
// one __syncthreads. Load latency hides behind interpolation; one barrier
// per channel instead of two, and it is not behind a cold vmcnt(0) drain.
// ---------------------------------------------------------------------------
__global__ __launch_bounds__(256) void warp_kernel(const float* __restrict__ vox,
                                                   const float* __restrict__ T,
                                                   float* __restrict__ out)
{
    __shared__ float lds[2 * BUF];                      // 32 KB
    const int tid = threadIdx.x;
    const int bid = blockIdx.x;
    const int n   = bid >> 9;                           // pose [0,8)
    const int t6  = bid & 511;
    const int ox  = (t6 & 7) << 3;
    const int oy  = ((t6 >> 3) & 7) << 3;
    const int oz  = (t6 >> 6) << 3;
    const int b   = n >> 2, j = n & 3;

    // zero-init both buffers: never-staged padding must be finite for
    // weight-0 reads.
    #pragma unroll
    for (int i = 0; i < 32; ++i) lds[tid + i * 256] = 0.0f;

    const float* Tn = T + n * 12;
    float R00 = Tn[0], R01 = Tn[1], R02 = Tn[2];
    float R10 = Tn[3], R11 = Tn[4], R12 = Tn[5];
    float R20 = Tn[6], R21 = Tn[7], R22 = Tn[8];
    float trx = Tn[9], try_ = Tn[10], trz = Tn[11];

    // ix = ax*gx + bx*gy + cx*gz + kx  (gx,gy,gz = output voxel index)
    const float S  = 1.0f / 64.0f;
    const float SC = 32.0f / 0.4921875f;
    const float ax = SC * R00 * S, bx = SC * R01 * S, cx = SC * R02 * S;
    const float ay = SC * R10 * S, by = SC * R11 * S, cy = SC * R12 * S;
    const float az = SC * R20 * S, bz = SC * R21 * S, cz = SC * R22 * S;
    const float kx = -31.5f * (ax + bx + cx) + SC * trx + 31.5f;
    const float ky = -31.5f * (ay + by + cy) + SC * try_ + 31.5f;
    const float kz = -31.5f * (az + bz + cz) + SC * trz + 31.5f;

    // bbox of sample coords over the tile (affine -> extrema at tile corners)
    float x0a = ax * ox, x0b = ax * (ox + 7);
    float x1a = bx * oy, x1b = bx * (oy + 7);
    float x2a = cx * oz, x2b = cx * (oz + 7);
    float min_ix = kx + fminf(x0a, x0b) + fminf(x1a, x1b) + fminf(x2a, x2b);
    float max_ix = kx + fmaxf(x0a, x0b) + fmaxf(x1a, x1b) + fmaxf(x2a, x2b);
    float y0a = ay * ox, y0b = ay * (ox + 7);
    float y1a = by * oy, y1b = by * (oy + 7);
    float y2a = cy * oz, y2b = cy * (oz + 7);
    float min_iy = ky + fminf(y0a, y0b) + fminf(y1a, y1b) + fminf(y2a, y2b);
    float max_iy = ky + fmaxf(y0a, y0b) + fmaxf(y1a, y1b) + fmaxf(y2a, y2b);
    float z0a = az * ox, z0b = az * (ox + 7);
    float z1a = bz * oy, z1b = bz * (ox ? oz : oz);     // placeholder no-op avoided below
    z1b = bz * (oy + 7);
    float z2a = cz * oz, z2b = cz * (oz + 7);
    float min_iz = kz + fminf(z0a, z0b) + fminf(bz * oy, z1b) + fminf(z2a, z2b);
    float max_iz = kz + fmaxf(z0a, z0b) + fmaxf(bz * oy, z1b) + fmaxf(z2a, z2b);

    int xlo = min(max((int)floorf(min_ix), 0), 63);
    int xhi = min(max((int)floorf(max_ix) + 1, 0), 63);
    int ylo = min(max((int)floorf(min_iy), 0), 63);
    int yhi = min(max((int)floorf(max_iy) + 1, 0), 63);
    int zlo = min(max((int)floorf(min_iz), 0), 63);
    int zhi = min(max((int)floorf(max_iz) + 1, 0), 63);
    int sx = xhi - xlo + 1;     // <= 15
    int sy = yhi - ylo + 1;
    int sz = zhi - zlo + 1;
    const int lstep = sy * LSTRIDE;

    // per-thread precompute for 2 outputs: weights + independently-clamped
    // corner addresses (reference semantics; round-2 bug fix retained).
    float w[2][6];
    int   ia[2][4], rxa[2][2], soff[2];
    #pragma unroll
    for (int k = 0; k < 2; ++k) {
        int o  = tid + (k << 8);
        int gx = ox + (o & 7);
        int gy = oy + ((o >> 3) & 7);
        int gz = oz + (o >> 6);
        float ix = kx + ax * gx + bx * gy + cx * gz;
        float iy = ky + ay * gx + by * gy + cy * gz;
        float iz = kz + az * gx + bz * gy + cz * gz;
        float fx = floorf(ix), fy = floorf(iy), fz = floorf(iz);
        float tx = ix - fx, ty = iy - fy, tz = iz - fz;
        int X0 = (int)fx, Y0 = (int)fy, Z0 = (int)fz;
        w[k][0] = ((unsigned)X0 < 64u) ? (1.0f - tx) : 0.0f;
        w[k][1] = ((unsigned)(X0 + 1) < 64u) ? tx : 0.0f;
        w[k][2] = ((unsigned)Y0 < 64u) ? (1.0f - ty) : 0.0f;
        w[k][3] = ((unsigned)(Y0 + 1) < 64u) ? ty : 0.0f;
        w[k][4] = ((unsigned)Z0 < 64u) ? (1.0f - tz) : 0.0f;
        w[k][5] = ((unsigned)(Z0 + 1) < 64u) ? tz : 0.0f;
        int rx0 = min(max(X0     - xlo, 0), sx - 1);
        int rx1 = min(max(X0 + 1 - xlo, 0), sx - 1);
        int ry0 = min(max(Y0     - ylo, 0), sy - 1) * LSTRIDE;
        int ry1 = min(max(Y0 + 1 - ylo, 0), sy - 1) * LSTRIDE;
        int rz0 = min(max(Z0     - zlo, 0), sz - 1) * lstep;
        int rz1 = min(max(Z0 + 1 - zlo, 0), sz - 1) * lstep;
        ia[k][0] = rz0 + ry0;
        ia[k][1] = rz0 + ry1;
        ia[k][2] = rz1 + ry0;
        ia[k][3] = rz1 + ry1;
        rxa[k][0] = rx0;
        rxa[k][1] = rx1;
        soff[k] = (gz << 12) + (gy << 6) + gx;
    }

    const size_t fb = (size_t)((b * TT + j + 1) * CCH) * G3_;
    const float* vbase = vox + fb;
    float* obase = out + fb;

    // staging assignment: 16 lanes cover x (row), 16 rows cover y; loop z.
    const int lane16 = tid & 15;
    const int row16  = tid >> 4;
    const bool act   = (lane16 < sx) && (row16 < sy);
    const int grow   = (zlo << 12) + ((ylo + row16) << 6) + xlo + lane16;
    const int lrow   = row16 * LSTRIDE + lane16;

    // prologue: stage channel 0 into buf0 (latency exposed once)
    if (act) {
        const float* gp = vbase + grow;
        int la = lrow;
        for (int zz = 0; zz < sz; ++zz) {
            lds[la] = gp[(size_t)zz << 12];
            la += lstep;
        }
    }
    __syncthreads();

    for (int c = 0; c < CCH; ++c) {
        // (1) issue global loads for channel c+1 into registers — no wait.
        float stg[MAXZ];
        const bool pre = (c + 1 < CCH);
        if (pre && act) {
            const float* gp = vbase + (size_t)(c + 1) * G3_ + grow;
            #pragma unroll
            for (int zz = 0; zz < MAXZ; ++zz) {
                if (zz < sz) stg[zz] = gp[(size_t)zz << 12];   // sz is uniform
            }
        }

        // (2) interpolate channel c from buf[c&1] (hides the load latency)
        const float* buf = lds + (c & 1) * BUF;
        float* op = obase + (size_t)c * G3_;
        #pragma unroll
        for (int k = 0; k < 2; ++k) {
            int r0 = rxa[k][0], r1 = rxa[k][1];
            float v000 = buf[ia[k][0] + r0], v001 = buf[ia[k][0] + r1];
            float v010 = buf[ia[k][1] + r0], v011 = buf[ia[k][1] + r1];
            float v100 = buf[ia[k][2] + r0], v101 = buf[ia[k][2] + r1];
            float v110 = buf[ia[k][3] + r0], v111 = buf[ia[k][3] + r1];
            float t00 = v000 * w[k][0] + v001 * w[k][1];
            float t01 = v010 * w[k][0] + v011 * w[k][1];
            float t10 = v100 * w[k][0] + v101 * w[k][1];
            float t11 = v110 * w[k][0] + v111 * w[k][1];
            float u0  = t00 * w[k][2] + t01 * w[k][3];
            float u1  = t10 * w[k][2] + t11 * w[k][3];
            op[soff[k]] = u0 * w[k][4] + u1 * w[k][5];
        }

        // (3) write the landed registers into buf[(c+1)&1]. Safe: the barrier
        // at the end of iteration c-1 guaranteed all waves finished reading
        // this buffer's previous contents.
        if (pre && act) {
            float* wbuf = lds + ((c + 1) & 1) * BUF;
            #pragma unroll
            for (int zz = 0; zz < MAXZ; ++zz) {
                if (zz < sz) wbuf[lrow + zz * lstep] = stg[zz];
            }
        }
        __syncthreads();
    }
}

extern "C" void kernel_launch(void* const* d_in, const int* in_sizes, int n_in,
                              void* d_out, int out_size, void* d_ws, size_t ws_size,
                              hipStream_t stream)
{
    const float* vox = (const float*)d_in[0];
    const float* cam = (const float*)d_in[1];
    float* out = (float*)d_out;
    float* Tws = (float*)d_ws;   // 8 poses * 12 floats

    hipLaunchKernelGGL(pose_kernel, dim3(1), dim3(64), 0, stream, cam, Tws);
    hipLaunchKernelGGL(copy0_kernel, dim3(8192), dim3(256), 0, stream, vox, out);
    hipLaunchKernelGGL(warp_kernel, dim3(4096), dim3(256), 0, stream, vox, Tws, out);
}